// Round 5
// baseline (15522.247 us; speedup 1.0000x reference)
//
#include <hip/hip_runtime.h>

// Problem constants (B,T,S,L,D_IN,OUT,W = 256,512,256,36,8,10,256)
#define Tt   512
#define Ll   36
#define DIN  8
#define OUTd 10

typedef __attribute__((ext_vector_type(8))) short short8;
typedef __attribute__((ext_vector_type(4))) float f32x4;

__device__ __forceinline__ unsigned short f2bf(float f) {
    union { float f; unsigned int u; } v; v.f = f;
    unsigned int r = v.u + 0x7fffu + ((v.u >> 16) & 1u);   // RNE
    return (unsigned short)(r >> 16);
}
__device__ __forceinline__ float bf2f(unsigned short u) {
    union { unsigned int u; float f; } v; v.u = ((unsigned int)u) << 16;
    return v.f;
}
__device__ __forceinline__ float sp_f(float x) {      // jax.nn.softplus
    return fmaxf(x, 0.f) + __logf(1.f + __expf(-fabsf(x)));
}
__device__ __forceinline__ float tanh_f(float x) {
    float e = __expf(2.f * x);
    return 1.f - 2.f / (e + 1.f);
}

// ---- agent-scope (sc1 / LLC-coherent) helpers: cross-XCD-safe ----
__device__ __forceinline__ unsigned long long ldg64(const void* p) {
    return __hip_atomic_load((const unsigned long long*)p, __ATOMIC_RELAXED, __HIP_MEMORY_SCOPE_AGENT);
}
__device__ __forceinline__ void stg64(void* p, unsigned long long v) {
    __hip_atomic_store((unsigned long long*)p, v, __ATOMIC_RELAXED, __HIP_MEMORY_SCOPE_AGENT);
}
__device__ __forceinline__ void sth(unsigned short* p, unsigned short v) {
    __hip_atomic_store(p, v, __ATOMIC_RELAXED, __HIP_MEMORY_SCOPE_AGENT);
}
union U64F2 { unsigned long long u; float f[2]; unsigned short s[4]; };

// ---- LDS layout ----
struct GScr {
    short hh[16*264], hl[16*264];      // gathered h(t), hi/lo bf16
    short z1h[16*264], z1l[16*264];    // stage-1 activations
    short z2h[16*264], z2l[16*264];    // stage-2 activations
    float lss[2*576];                  // logsigs slice, double-buffered (prefetch t+1)
    float ml[16*584];                  // tanh(m) slice [16 rows x 576 n]
};                                      // ~92.7 KB
struct IScr { float x0s[32][DIN]; float h1[32*257]; float h2[32*257]; };
union  Scr  { GScr g; IScr in; };

// ---- full-grid tree barrier (phase 0 only); touches slots[0 .. 512] inclusive ----
__device__ __forceinline__ void gbar(int* bar, int gen) {
    __syncthreads();
    if (threadIdx.x == 0) {
        const int g = blockIdx.x & 7;
        int old = __hip_atomic_fetch_add(bar + g * 32, 1, __ATOMIC_RELAXED, __HIP_MEMORY_SCOPE_AGENT);
        if (old == gen * 32 - 1) {
            int o2 = __hip_atomic_fetch_add(bar + 8 * 32, 1, __ATOMIC_RELAXED, __HIP_MEMORY_SCOPE_AGENT);
            if (o2 == gen * 8 - 1) {
#pragma unroll
                for (int gg = 0; gg < 8; ++gg)
                    __hip_atomic_store(bar + (9 + gg) * 32, gen, __ATOMIC_RELAXED, __HIP_MEMORY_SCOPE_AGENT);
            }
        }
        while (__hip_atomic_load(bar + (9 + g) * 32, __ATOMIC_RELAXED, __HIP_MEMORY_SCOPE_AGENT) < gen)
            __builtin_amdgcn_s_sleep(2);
    }
    __syncthreads();
}

// ---- chunk-local barrier: 16 blocks on one monotone counter ----
__device__ __forceinline__ void cbar(int* c, int gen) {
    __syncthreads();   // drains each wave's sc1 stores (vmcnt 0) before arrive
    if (threadIdx.x == 0) {
        __hip_atomic_fetch_add(c, 1, __ATOMIC_RELAXED, __HIP_MEMORY_SCOPE_AGENT);
        while (__hip_atomic_load(c, __ATOMIC_RELAXED, __HIP_MEMORY_SCOPE_AGENT) < gen * 16)
            __builtin_amdgcn_s_sleep(1);
    }
    __syncthreads();
}

// cast 8 consecutive k of W[n][k] (N x 256) into frag-contiguous transposed layout:
// element (n,k) -> ((k>>5)*N + n)*32 + ((k>>3)&3)*8 + (k&7)
__device__ __forceinline__ void cast_w8n(const float* src, unsigned short* dh,
                                         unsigned short* dl, long u, int N) {
    long n = u >> 5; int k8 = (int)(u & 31);
    const float* sp = src + n * 256 + k8 * 8;
    f32x4 f0 = *(const f32x4*)sp;
    f32x4 f1 = *(const f32x4*)(sp + 4);
    U64F2 H0, H1, L0, L1;
#pragma unroll
    for (int q = 0; q < 4; ++q) {
        unsigned short a = f2bf(f0[q]); H0.s[q] = a; L0.s[q] = f2bf(f0[q] - bf2f(a));
        unsigned short b = f2bf(f1[q]); H1.s[q] = b; L1.s[q] = f2bf(f1[q] - bf2f(b));
    }
    long d = ((long)(k8 >> 2) * N + n) * 32 + (k8 & 3) * 8;
    stg64(dh + d, H0.u);  stg64(dh + d + 4, H1.u);
    stg64(dl + d, L0.u);  stg64(dl + d + 4, L1.u);
}

// one MLP stage for 16 rows, 8-wave version: each wave owns 2 n-tiles (2*wv+j).
// Z = softplus(A @ B^T + bias); A/Z in LDS [16][264] hi/lo, B global frag-contiguous.
#define MLP_STAGE16(Ah, Al, Bh, Bl, BIAS, Zh, Zl) do {                                      \
    f32x4 acc_[2] = {zero4, zero4};                                                          \
    for (int k0_ = 0; k0_ < 256; k0_ += 32) {                                                \
      short8 ah_ = *(const short8*)(const void*)&(Ah)[l15 * 264 + k0_ + quad * 8];           \
      short8 al_ = *(const short8*)(const void*)&(Al)[l15 * 264 + k0_ + quad * 8];           \
      _Pragma("unroll")                                                                      \
      for (int j_ = 0; j_ < 2; ++j_) {                                                       \
        int n_ = (2 * wv + j_) * 16 + l15;                                                   \
        long bo_ = ((long)(k0_ >> 5) * 256 + n_) * 32 + quad * 8;                            \
        short8 bh_ = *(const short8*)(const void*)((Bh) + bo_);                              \
        short8 bl_ = *(const short8*)(const void*)((Bl) + bo_);                              \
        acc_[j_] = __builtin_amdgcn_mfma_f32_16x16x32_bf16(ah_, bh_, acc_[j_], 0, 0, 0);     \
        acc_[j_] = __builtin_amdgcn_mfma_f32_16x16x32_bf16(ah_, bl_, acc_[j_], 0, 0, 0);     \
        acc_[j_] = __builtin_amdgcn_mfma_f32_16x16x32_bf16(al_, bh_, acc_[j_], 0, 0, 0);     \
      }                                                                                      \
    }                                                                                        \
    _Pragma("unroll")                                                                        \
    for (int j_ = 0; j_ < 2; ++j_) {                                                         \
      int n_ = (2 * wv + j_) * 16 + l15;                                                     \
      float bs_ = (BIAS)[n_];                                                                \
      _Pragma("unroll")                                                                      \
      for (int r_ = 0; r_ < 4; ++r_) {                                                       \
        int row_ = quad * 4 + r_;                                                            \
        float v_ = sp_f(acc_[j_][r_] + bs_);                                                 \
        unsigned short hi_ = f2bf(v_);                                                       \
        (Zh)[row_ * 264 + n_] = (short)hi_;                                                  \
        (Zl)[row_ * 264 + n_] = (short)f2bf(v_ - bf2f(hi_));                                 \
      }                                                                                      \
    }                                                                                        \
  } while (0)

__global__ __launch_bounds__(512, 1) void rde_fused5(
    const float* __restrict__ x0, const float* __restrict__ logsigs,
    const float* __restrict__ iW1, const float* __restrict__ ib1,
    const float* __restrict__ iW2, const float* __restrict__ ib2,
    const float* __restrict__ iW3, const float* __restrict__ ib3,
    const float* __restrict__ vW1, const float* __restrict__ vb1,
    const float* __restrict__ vW2, const float* __restrict__ vb2,
    const float* __restrict__ vW3, const float* __restrict__ vb3,
    const float* __restrict__ roW, const float* __restrict__ rob,
    float* __restrict__ out,
    unsigned short* hhA, unsigned short* hlA,
    unsigned short* hhB, unsigned short* hlB,
    unsigned short* w1th, unsigned short* w1tl,
    unsigned short* w2th, unsigned short* w2tl,
    unsigned short* w3th, unsigned short* w3tl, int* slots) {
    __shared__ Scr S;
    __shared__ float hloc[256];   // owned h sub-tile [16 rows x 16 s], exact f32
    __shared__ float rtmp[84];    // readout partials (8 waves x 10)
    const int tid = threadIdx.x, blk = blockIdx.x;
    const int lane = tid & 63, wv = tid >> 6, quad = lane >> 4, l15 = lane & 15;
    // blk bits: b0-2 = xcd-ish, b3-6 = chunk, b7 = slot parity.
    // slot = ((blk&7)<<1)|(blk>>7): each XCD's 32 blocks share only 2 W3 slices (1.2 MB).
    const int chunk = (blk >> 3) & 15;
    const int sl = ((blk & 7) << 1) | (blk >> 7);
    const int b0c16 = chunk * 16;        // 16 batch rows owned by this chunk
    const int s0g = sl * 16;             // owned s-slice
    const int n0g = sl * 576;            // owned W3 n-slice
    // chunk counters at slots+1024: DISJOINT from gbar's range [0, 512]
    int* cb = slots + 1024 + chunk * 32;
    const f32x4 zero4 = {0.f, 0.f, 0.f, 0.f};
    // W3 n-tile assignment: wave wv owns tiles {wv, wv+8, wv+16, wv+24} (+ 32+wv if wv<4)
    const int nnt = (wv < 4) ? 5 : 4;

    // ===== phase 0: init MLP (blk<8), W1/W2 cast (8..15), W3 transposed cast (16..255) =====
    if (blk < 8) {
        IScr& I = S.in;
        const int b0 = blk * 32;
        if (tid < 256) I.x0s[tid >> 3][tid & 7] = x0[(b0 + (tid >> 3)) * DIN + (tid & 7)];
        __syncthreads();
        const int j = tid;
        if (tid < 256) {
            float w[DIN];
#pragma unroll
            for (int k = 0; k < DIN; ++k) w[k] = iW1[j * DIN + k];
            float bias = ib1[j];
            for (int r = 0; r < 32; ++r) {
                float acc = bias;
#pragma unroll
                for (int k = 0; k < DIN; ++k) acc += I.x0s[r][k] * w[k];
                I.h1[r * 257 + j] = sp_f(acc);
            }
        }
        __syncthreads();
        if (tid < 256) {
            float bias = ib2[j];
            for (int rb = 0; rb < 4; ++rb) {
                float a8[8];
#pragma unroll
                for (int rr = 0; rr < 8; ++rr) a8[rr] = bias;
                for (int k = 0; k < 256; ++k) {
                    float wvv = iW2[j * 256 + k];
#pragma unroll
                    for (int rr = 0; rr < 8; ++rr) a8[rr] += I.h1[(rb * 8 + rr) * 257 + k] * wvv;
                }
#pragma unroll
                for (int rr = 0; rr < 8; ++rr) I.h2[(rb * 8 + rr) * 257 + j] = sp_f(a8[rr]);
            }
        }
        __syncthreads();
        if (tid < 256) {
            float bias = ib3[j];
            for (int rb = 0; rb < 4; ++rb) {
                float a8[8];
#pragma unroll
                for (int rr = 0; rr < 8; ++rr) a8[rr] = bias;
                for (int k = 0; k < 256; ++k) {
                    float wvv = iW3[j * 256 + k];
#pragma unroll
                    for (int rr = 0; rr < 8; ++rr) a8[rr] += I.h2[(rb * 8 + rr) * 257 + k] * wvv;
                }
#pragma unroll
                for (int rr = 0; rr < 8; ++rr) {   // publish h0 pre-split
                    float v = a8[rr];
                    unsigned short hi = f2bf(v);
                    sth(&hhA[(b0 + rb * 8 + rr) * 256 + j], hi);
                    sth(&hlA[(b0 + rb * 8 + rr) * 256 + j], f2bf(v - bf2f(hi)));
                }
            }
        }
    } else if (blk < 16) {
        const int idx = blk - 8;
        const float* src = (idx < 4) ? vW1 : vW2;
        unsigned short* dh = (idx < 4) ? w1th : w2th;
        unsigned short* dl = (idx < 4) ? w1tl : w2tl;
        const int part = idx & 3;
        for (int u = part * 2048 + tid; u < (part + 1) * 2048; u += 512)
            cast_w8n(src, dh, dl, u, 256);
    } else {
        for (long u = (long)(blk - 16) * 512 + tid; u < 9216L * 32; u += 240L * 512)
            cast_w8n(vW3, w3th, w3tl, u, 9216);
    }
    gbar(slots, 1);

    // init owned h sub-tile (hi+lo reconstruction, ~1e-5 rel)
    if (tid < 64) {
        int r = tid >> 2, sq = tid & 3;
        U64F2 a, b;
        a.u = ldg64(hhA + (b0c16 + r) * 256 + s0g + sq * 4);
        b.u = ldg64(hlA + (b0c16 + r) * 256 + s0g + sq * 4);
#pragma unroll
        for (int q = 0; q < 4; ++q) hloc[r * 16 + sq * 4 + q] = bf2f(a.s[q]) + bf2f(b.s[q]);
    }
    // prefetch logsigs slice for t=0 into buffer 0
    for (int i = tid; i < 16 * Ll; i += 512) {
        int r = i / Ll, l = i - r * Ll;
        S.g.lss[i] = logsigs[((long)(b0c16 + r) * Tt) * Ll + l];
    }

    // ================= main scan: one chunk-local barrier per step =================
    int lgen = 0;
    for (int t = 0; t < Tt; ++t) {
        GScr& G = S.g;
        const unsigned short* hhs = (t & 1) ? hhB : hhA;
        const unsigned short* hls = (t & 1) ? hlB : hlA;
        unsigned short* hhd = (t & 1) ? hhA : hhB;
        unsigned short* hld = (t & 1) ? hlA : hlB;

        // ---- gather h(t) [16 rows x 256] hi/lo into LDS (coalesced u64 copies) ----
        for (int u = tid; u < 1024; u += 512) {
            int r = u >> 6, c4 = (u & 63) * 4;
            *(unsigned long long*)(void*)&G.hh[r * 264 + c4] = ldg64(hhs + (b0c16 + r) * 256 + c4);
            *(unsigned long long*)(void*)&G.hl[r * 264 + c4] = ldg64(hls + (b0c16 + r) * 256 + c4);
        }
        __syncthreads();

        // ---- readout partials for row b0c16+sl: wave wv covers s in [wv*32, wv*32+32) ----
        if (lane < OUTd) {
            const int o = lane;
            float acc = 0.f;
            const short* ph = &G.hh[sl * 264 + wv * 32];
            const short* pl = &G.hl[sl * 264 + wv * 32];
            const float* wp = roW + o * 256 + wv * 32;
            for (int s = 0; s < 32; s += 8) {
                short8 vh = *(const short8*)(const void*)(ph + s);
                short8 vl = *(const short8*)(const void*)(pl + s);
                f32x4 w0 = *(const f32x4*)(wp + s);
                f32x4 w1 = *(const f32x4*)(wp + s + 4);
#pragma unroll
                for (int q = 0; q < 4; ++q) {
                    acc += (bf2f((unsigned short)vh[q]) + bf2f((unsigned short)vl[q])) * w0[q];
                    acc += (bf2f((unsigned short)vh[q + 4]) + bf2f((unsigned short)vl[q + 4])) * w1[q];
                }
            }
            rtmp[wv * 10 + o] = acc;
        }

        // ---- stage 1: z1 = sp(h W1^T) ----
        MLP_STAGE16(G.hh, G.hl, w1th, w1tl, vb1, G.z1h, G.z1l);
        __syncthreads();

        if (tid < OUTd) {
            float acc = rob[tid];
#pragma unroll
            for (int w = 0; w < 8; ++w) acc += rtmp[w * 10 + tid];
            out[((long)(b0c16 + sl) * 513 + t) * OUTd + tid] = acc;
        }

        // ---- stage 2: z2 = sp(z1 W2^T) ----
        MLP_STAGE16(G.z1h, G.z1l, w2th, w2tl, vb2, G.z2h, G.z2l);
        __syncthreads();

        // ---- W3 GEMM: m-pre = z2 @ W3slice^T (B direct from global, L2-resident) ----
        {
            f32x4 acc[5];
#pragma unroll
            for (int i = 0; i < 5; ++i) acc[i] = zero4;
            for (int kk = 0; kk < 8; ++kk) {
                short8 ah = *(const short8*)(const void*)&G.z2h[l15 * 264 + kk * 32 + quad * 8];
                short8 al = *(const short8*)(const void*)&G.z2l[l15 * 264 + kk * 32 + quad * 8];
#pragma unroll
                for (int i = 0; i < 5; ++i) {
                    if (i < nnt) {
                        int tile = wv + 8 * i;           // i==4 only when wv<4: tile=32+wv
                        long n = (long)n0g + tile * 16 + l15;
                        long bo = ((long)kk * 9216 + n) * 32 + quad * 8;
                        short8 bh = *(const short8*)(const void*)(w3th + bo);
                        short8 bl = *(const short8*)(const void*)(w3tl + bo);
                        acc[i] = __builtin_amdgcn_mfma_f32_16x16x32_bf16(ah, bh, acc[i], 0, 0, 0);
                        acc[i] = __builtin_amdgcn_mfma_f32_16x16x32_bf16(ah, bl, acc[i], 0, 0, 0);
                        acc[i] = __builtin_amdgcn_mfma_f32_16x16x32_bf16(al, bh, acc[i], 0, 0, 0);
                    }
                }
            }
            // tanh epilogue -> ml
#pragma unroll
            for (int i = 0; i < 5; ++i) {
                if (i < nnt) {
                    int tile = wv + 8 * i;
                    int nloc = tile * 16 + l15;
                    float bias = vb3[n0g + nloc];
#pragma unroll
                    for (int r = 0; r < 4; ++r) {
                        int row = quad * 4 + r;
                        G.ml[row * 584 + nloc] = tanh_f(acc[i][r] + bias);
                    }
                }
            }
        }
        __syncthreads();

        // ---- l-contraction: thread (r, s) owns h[r][s0g+s]: hloc += dot36 ----
        if (tid < 256) {
            int r = tid >> 4, sL = tid & 15;
            const f32x4* mp = (const f32x4*)(const void*)&G.ml[r * 584 + sL * 36];
            const f32x4* lp = (const f32x4*)(const void*)&G.lss[(t & 1) * 576 + r * 36];
            float a = 0.f;
#pragma unroll
            for (int q = 0; q < 9; ++q) {
                f32x4 m4 = mp[q], l4 = lp[q];
                a += m4[0] * l4[0] + m4[1] * l4[1] + m4[2] * l4[2] + m4[3] * l4[3];
            }
            hloc[tid] += a;
        }
        __syncthreads();

        // ---- publish owned h sub-tile pre-split to the other buffer ----
        if (tid < 64) {
            int r = tid >> 2, sq = tid & 3;
            U64F2 H, L;
#pragma unroll
            for (int q = 0; q < 4; ++q) {
                float v = hloc[r * 16 + sq * 4 + q];
                unsigned short hi = f2bf(v);
                H.s[q] = hi;
                L.s[q] = f2bf(v - bf2f(hi));
            }
            stg64(hhd + (b0c16 + r) * 256 + s0g + sq * 4, H.u);
            stg64(hld + (b0c16 + r) * 256 + s0g + sq * 4, L.u);
        }
        // ---- prefetch logsigs(t+1) into the other lss buffer (h-independent) ----
        if (t + 1 < Tt) {
            for (int i = tid; i < 16 * Ll; i += 512) {
                int r = i / Ll, l = i - r * Ll;
                G.lss[((t + 1) & 1) * 576 + i] =
                    logsigs[((long)(b0c16 + r) * Tt + (t + 1)) * Ll + l];
            }
        }
        cbar(cb, ++lgen);
    }

    // ---- final readout out[:, 512, :]: row b0c16+sl, h(512) in A buffers (Tt even) ----
    {
        float* fb = S.g.ml;   // reuse as f32 row buffer
        if (tid < 64) {
            U64F2 a, b;
            a.u = ldg64(hhA + (long)(b0c16 + sl) * 256 + tid * 4);
            b.u = ldg64(hlA + (long)(b0c16 + sl) * 256 + tid * 4);
#pragma unroll
            for (int q = 0; q < 4; ++q) fb[tid * 4 + q] = bf2f(a.s[q]) + bf2f(b.s[q]);
        }
        __syncthreads();
        if (tid < OUTd) {
            float acc = rob[tid];
            const float* wp = roW + tid * 256;
            for (int s = 0; s < 256; s += 4) {
                f32x4 hv = *(const f32x4*)(fb + s);
                f32x4 w4 = *(const f32x4*)(wp + s);
                acc += hv[0] * w4[0] + hv[1] * w4[1] + hv[2] * w4[2] + hv[3] * w4[3];
            }
            out[((long)(b0c16 + sl) * 513 + Tt) * OUTd + tid] = acc;
        }
    }
}

extern "C" void kernel_launch(void* const* d_in, const int* in_sizes, int n_in,
                              void* d_out, int out_size, void* d_ws, size_t ws_size,
                              hipStream_t stream) {
    const float* x0      = (const float*)d_in[0];
    const float* logsigs = (const float*)d_in[1];
    const float* iW1 = (const float*)d_in[2];
    const float* ib1 = (const float*)d_in[3];
    const float* iW2 = (const float*)d_in[4];
    const float* ib2 = (const float*)d_in[5];
    const float* iW3 = (const float*)d_in[6];
    const float* ib3 = (const float*)d_in[7];
    const float* vW1 = (const float*)d_in[8];
    const float* vb1 = (const float*)d_in[9];
    const float* vW2 = (const float*)d_in[10];
    const float* vb2 = (const float*)d_in[11];
    const float* vW3 = (const float*)d_in[12];
    const float* vb3 = (const float*)d_in[13];
    const float* roW = (const float*)d_in[14];
    const float* rob = (const float*)d_in[15];
    float* out = (float*)d_out;

    char* p = (char*)d_ws;
    unsigned short* hhA  = (unsigned short*)p;                // 131072 B
    unsigned short* hlA  = (unsigned short*)(p + 131072);     // 131072 B
    unsigned short* hhB  = (unsigned short*)(p + 262144);     // 131072 B
    unsigned short* hlB  = (unsigned short*)(p + 393216);     // 131072 B
    unsigned short* w1th = (unsigned short*)(p + 524288);     // 131072 B
    unsigned short* w1tl = (unsigned short*)(p + 655360);     // 131072 B
    unsigned short* w2th = (unsigned short*)(p + 786432);     // 131072 B
    unsigned short* w2tl = (unsigned short*)(p + 917504);     // 131072 B
    unsigned short* w3th = (unsigned short*)(p + 1048576);    // 4718592 B
    unsigned short* w3tl = (unsigned short*)(p + 5767168);    // 4718592 B
    int* slots           = (int*)(p + 10485760);              // barriers: gbar [0,512], cbar [1024,1504]

    hipMemsetAsync(slots, 0, 8192, stream);
    rde_fused5<<<dim3(256), dim3(512), 0, stream>>>(
        x0, logsigs, iW1, ib1, iW2, ib2, iW3, ib3,
        vW1, vb1, vW2, vb2, vW3, vb3, roW, rob, out,
        hhA, hlA, hhB, hlB, w1th, w1tl, w2th, w2tl, w3th, w3tl, slots);
}